// Round 1
// baseline (442.678 us; speedup 1.0000x reference)
//
#include <hip/hip_runtime.h>

// out[b,h,t,f] = sum_{r=0..64} a[b,h,t,r] * v[b,h, t+r-32, f]   (zero-padded in t)
// B=8 H=16 T=4096 F=64 R=65, all fp32.
//
// Strategy: block = 256 threads = 4 waves, handles TILE_T=128 output rows of one
// (b,h) slab, all 64 features. v tile (192 rows x 64 f = 48KB) staged in LDS once.
// Each wave owns 32 rows: acc[32] in VGPRs; r-loop chunked by 13 with a register
// window vbuf[44] so each LDS value is reused ~6.9x. a reads are wave-uniform
// (lane = feature) -> scalar loads via readfirstlane-forced uniform base.

#define TILE_T 128
#define NT 32          // output rows per wave
#define RC 13          // r-chunk size (65 = 5*13)
#define RR 65
#define FF 64
#define HALO 32        // RR/2
#define WROWS (TILE_T + RR - 1)   // 192 staged rows

__global__ __launch_bounds__(256, 2)
void unfold_kernel(const float* __restrict__ a, const float* __restrict__ v,
                   float* __restrict__ out, int T) {
    __shared__ float sv[WROWS * FF];  // 48 KB

    const int tid = threadIdx.x;
    const int tilesPerBH = T / TILE_T;            // 32
    const int bh   = blockIdx.x / tilesPerBH;
    const int tile = blockIdx.x % tilesPerBH;
    const int t0 = tile * TILE_T;

    const size_t vbase = (size_t)bh * T * FF;

    // ---- stage v rows [t0-32, t0+160) into LDS (contiguous copy, float4) ----
    const int g0 = t0 - HALO;
    #pragma unroll
    for (int q = 0; q < (WROWS * FF / 4) / 256; ++q) {   // 12 iterations
        int lin = tid + q * 256;         // float4 index within tile
        int row = lin >> 4;              // 16 float4 per row
        int f4  = lin & 15;
        int g = g0 + row;
        float4 val = make_float4(0.f, 0.f, 0.f, 0.f);
        if (g >= 0 && g < T)
            val = *reinterpret_cast<const float4*>(v + vbase + (size_t)g * FF + f4 * 4);
        *reinterpret_cast<float4*>(&sv[row * FF + f4 * 4]) = val;
    }
    __syncthreads();

    // ---- compute: wave w owns rows [t0 + w*32, +32), lane = feature ----
    const int lane = tid & 63;
    const int wave = __builtin_amdgcn_readfirstlane(tid >> 6);  // force uniform
    const int tw = t0 + wave * NT;
    const float* aw = a + ((size_t)bh * T + tw) * RR;           // uniform base -> s_load

    float acc[NT];
    #pragma unroll
    for (int i = 0; i < NT; ++i) acc[i] = 0.f;

    const int wbase = wave * NT;
    for (int c = 0; c < RR / RC; ++c) {              // 5 chunks, runtime loop
        float vbuf[NT + RC - 1];                     // 44 regs
        #pragma unroll
        for (int j = 0; j < NT + RC - 1; ++j)
            vbuf[j] = sv[(wbase + c * RC + j) * FF + lane];
        #pragma unroll
        for (int i = 0; i < NT; ++i) {
            #pragma unroll
            for (int k = 0; k < RC; ++k)
                acc[i] = fmaf(aw[i * RR + c * RC + k], vbuf[i + k], acc[i]);
        }
    }

    float* ow = out + ((size_t)bh * T + tw) * FF + lane;
    #pragma unroll
    for (int i = 0; i < NT; ++i)
        ow[(size_t)i * FF] = acc[i];
}

extern "C" void kernel_launch(void* const* d_in, const int* in_sizes, int n_in,
                              void* d_out, int out_size, void* d_ws, size_t ws_size,
                              hipStream_t stream) {
    const float* a = (const float*)d_in[0];
    const float* v = (const float*)d_in[1];
    float* out = (float*)d_out;

    const int T = 4096;
    const int BH = in_sizes[1] / (T * FF);   // 128
    const int grid = BH * (T / TILE_T);      // 4096 blocks

    unfold_kernel<<<grid, 256, 0, stream>>>(a, v, out, T);
}

// Round 2
// 205.219 us; speedup vs baseline: 2.1571x; 2.1571x over previous
//
#include <hip/hip_runtime.h>

// out[b,h,t,f] = sum_{r=0..64} a[b,h,t,r] * v[b,h, t+r-32, f]   (zero-padded in t)
// B=8 H=16 T=4096 F=64 R=65, all fp32.
//
// Round 2: kill the scalar-load (SMEM) stall. a now staged in LDS as interleaved
// row-pairs so the inner loop reads it with ds_read_b64 BROADCASTS (in-order DS,
// partial lgkmcnt waits) instead of out-of-order s_loads that forced lgkmcnt(0)
// drains. TILE_T=64 keeps sv(32KB)+sa(16.6KB) at 3 blocks/CU (12 waves).

#define TILE_T 64
#define NT 16          // output rows per wave
#define RC 13          // r-chunk size (65 = 5*13)
#define RR 65
#define FF 64
#define HALO 32        // RR/2
#define WROWS (TILE_T + RR - 1)   // 128 staged v rows

__global__ __launch_bounds__(256, 3)
void unfold_kernel(const float* __restrict__ a, const float* __restrict__ v,
                   float* __restrict__ out, int T) {
    __shared__ float sv[WROWS * FF];               // 32768 B
    __shared__ float sa2[(TILE_T / 2) * (2 * RR)]; // 16640 B, row-pair interleaved

    const int tid = threadIdx.x;
    const int tilesPerBH = T / TILE_T;            // 64
    const int bh   = blockIdx.x / tilesPerBH;
    const int tile = blockIdx.x % tilesPerBH;
    const int t0 = tile * TILE_T;

    const size_t vbase = (size_t)bh * T * FF;

    // ---- stage v rows [t0-32, t0+96) into LDS (contiguous, float4) ----
    const int g0 = t0 - HALO;
    #pragma unroll
    for (int q = 0; q < (WROWS * FF / 4) / 256; ++q) {   // 8 iterations
        int lin = tid + q * 256;         // float4 index within tile
        int row = lin >> 4;              // 16 float4 per row
        int f4  = lin & 15;
        int g = g0 + row;
        float4 val = make_float4(0.f, 0.f, 0.f, 0.f);
        if (g >= 0 && g < T)
            val = *reinterpret_cast<const float4*>(v + vbase + (size_t)g * FF + f4 * 4);
        *reinterpret_cast<float4*>(&sv[row * FF + f4 * 4]) = val;
    }

    // ---- stage a rows [t0, t0+64) as interleaved pairs:
    //      sa2[(i/2)*130 + r*2 + (i&1)] = a[t0+i, r]  -> ds_read_b64 broadcast pairs
    const float* ab = a + ((size_t)bh * T + t0) * RR;
    #pragma unroll
    for (int q = 0; q < 17; ++q) {                 // 17*256 = 4352 >= 4160
        int lin = tid + q * 256;
        if (lin < TILE_T * RR) {
            float val = ab[lin];
            int i = lin / RR;
            int r = lin - i * RR;
            sa2[(i >> 1) * (2 * RR) + r * 2 + (i & 1)] = val;
        }
    }
    __syncthreads();

    // ---- compute: wave w owns rows [t0 + w*16, +16), lane = feature ----
    const int lane = tid & 63;
    const int wave = __builtin_amdgcn_readfirstlane(tid >> 6);
    const int wbase = wave * NT;

    float acc[NT];
    #pragma unroll
    for (int i = 0; i < NT; ++i) acc[i] = 0.f;

    #pragma unroll 1
    for (int c = 0; c < RR / RC; ++c) {            // 5 chunks
        float vbuf[NT + RC - 1];                   // 28 regs, sliding window
        #pragma unroll
        for (int j = 0; j < NT + RC - 1; ++j)
            vbuf[j] = sv[(wbase + c * RC + j) * FF + lane];

        #pragma unroll
        for (int p = 0; p < NT / 2; ++p) {         // 8 row pairs
            const int pr = (wbase >> 1) + p;
            const float2* apptr =
                reinterpret_cast<const float2*>(&sa2[pr * (2 * RR) + c * RC * 2]);
            float2 ap[RC];
            #pragma unroll
            for (int k = 0; k < RC; ++k) ap[k] = apptr[k];   // b64 broadcasts
            #pragma unroll
            for (int k = 0; k < RC; ++k) {
                acc[2 * p]     = fmaf(ap[k].x, vbuf[2 * p + k],     acc[2 * p]);
                acc[2 * p + 1] = fmaf(ap[k].y, vbuf[2 * p + 1 + k], acc[2 * p + 1]);
            }
        }
    }

    float* ow = out + ((size_t)bh * T + t0 + wbase) * FF + lane;
    #pragma unroll
    for (int i = 0; i < NT; ++i)
        ow[(size_t)i * FF] = acc[i];
}

extern "C" void kernel_launch(void* const* d_in, const int* in_sizes, int n_in,
                              void* d_out, int out_size, void* d_ws, size_t ws_size,
                              hipStream_t stream) {
    const float* a = (const float*)d_in[0];
    const float* v = (const float*)d_in[1];
    float* out = (float*)d_out;

    const int T = 4096;
    const int BH = in_sizes[1] / (T * FF);   // 128
    const int grid = BH * (T / TILE_T);      // 8192 blocks

    unfold_kernel<<<grid, 256, 0, stream>>>(a, v, out, T);
}

// Round 3
// 105.540 us; speedup vs baseline: 4.1944x; 1.9445x over previous
//
#include <hip/hip_runtime.h>

// out[b,h,t,f] = sum_{r=0..64} a[b,h,t,r] * v[b,h, t+r-32, f]  (zero-padded in t)
// B=8 H=16 T=4096 F=64 R=65, fp32 in/out. Threshold 1.0 -> bf16 MFMA is safe.
//
// Banded matmul on matrix cores: per 32-row tile,
//   OUT(32x64) = Ablk(32x96) x Vslice(96x64),
//   Ablk[i][c] = (0 <= c-i <= 64) ? a[t0+i][c-i] : 0.
// Block = 256 thr (4 waves) handles 128 rows; sa = band-densified bf16 a
// (zero-prefilled, aligned quad scatter), sv = transposed bf16 v (lane=feature
// staging: coalesced reads, aligned packed writes). 52 KB LDS -> 3 blocks/CU.

#define TT 4096
#define RRR 65
#define FF 64
#define TILE 128
#define SA_S 104     // bf16 row stride (16B-aligned rows, mild 4-way ok)
#define SV_S 200     // bf16 row stride

typedef short bf16x8 __attribute__((ext_vector_type(8)));
typedef float f32x16 __attribute__((ext_vector_type(16)));

__device__ __forceinline__ unsigned short f2bf(float x) {
    unsigned int u = __float_as_uint(x);
    u += 0x7fff + ((u >> 16) & 1);            // RNE
    return (unsigned short)(u >> 16);
}

__global__ __launch_bounds__(256, 3)
void unfold_mfma(const float* __restrict__ a, const float* __restrict__ v,
                 float* __restrict__ out) {
    __shared__ __align__(16) unsigned short sa[TILE * SA_S];  // 26624 B
    __shared__ __align__(16) unsigned short sv[FF * SV_S];    // 25600 B

    const int tid  = threadIdx.x;
    const int bh   = blockIdx.x >> 5;       // 32 tiles per (b,h)
    const int tile = blockIdx.x & 31;
    const int t0   = tile << 7;

    const float* arow = a + ((size_t)bh * TT + t0) * RRR;
    const float* vsl  = v + (size_t)bh * TT * FF;

    // ---- zero-prefill sa (band complement must be 0) ----
    {
        uint4 z = make_uint4(0, 0, 0, 0);
        uint4* sp = (uint4*)sa;
        #pragma unroll
        for (int it = 0; it < 7; ++it) {
            int lin = tid + it * 256;
            if (lin < (TILE * SA_S) / 8) sp[lin] = z;
        }
    }

    // ---- preload a (consumed after barrier; hides VMEM latency) ----
    // per row R: quads at r = r0+4j, j<15 (aligned: (R*65+r0)%4==0), + 5 edge elems
    float4 aq[8];
    #pragma unroll
    for (int it = 0; it < 8; ++it) {
        int lin = tid + it * 256;
        if (lin < TILE * 15) {
            int R = lin / 15, j = lin - R * 15;
            int r0 = (4 - (R & 3)) & 3;
            aq[it] = *(const float4*)(arow + (size_t)R * RRR + r0 + 4 * j);
        }
    }
    float ae[3];
    #pragma unroll
    for (int it = 0; it < 3; ++it) {
        int lin = tid + it * 256;
        if (lin < TILE * 5) {
            int R = lin / 5, e = lin - R * 5;
            int r0 = (4 - (R & 3)) & 3;
            int r = (e < r0) ? e : 60 + e;    // head [0,r0) + tail [r0+60,64]
            ae[it] = arow[(size_t)R * RRR + r];
        }
    }

    // ---- stage v transposed: sv[f][c] = bf16(v[t0-32+c][f]), c in [0,192) ----
    {
        const int f  = tid & 63;
        const int wv = tid >> 6;
        #pragma unroll
        for (int it = 0; it < 12; ++it) {
            int cb = 4 * (wv * 12 + it);
            int g  = t0 - 32 + cb;
            float x0 = (g + 0 >= 0 && g + 0 < TT) ? vsl[(size_t)(g + 0) * FF + f] : 0.f;
            float x1 = (g + 1 >= 0 && g + 1 < TT) ? vsl[(size_t)(g + 1) * FF + f] : 0.f;
            float x2 = (g + 2 >= 0 && g + 2 < TT) ? vsl[(size_t)(g + 2) * FF + f] : 0.f;
            float x3 = (g + 3 >= 0 && g + 3 < TT) ? vsl[(size_t)(g + 3) * FF + f] : 0.f;
            uint2 pk;
            pk.x = (unsigned)f2bf(x0) | ((unsigned)f2bf(x1) << 16);
            pk.y = (unsigned)f2bf(x2) | ((unsigned)f2bf(x3) << 16);
            *(uint2*)&sv[f * SV_S + cb] = pk;
        }
    }

    __syncthreads();   // prefill complete before band scatter

    // ---- scatter a band: sa[R][ (R&31) + r ] = bf16(a[t0+R][r]) ----
    #pragma unroll
    for (int it = 0; it < 8; ++it) {
        int lin = tid + it * 256;
        if (lin < TILE * 15) {
            int R = lin / 15, j = lin - R * 15;
            int r0 = (4 - (R & 3)) & 3;
            int rq = r0 + 4 * j;
            float4 q = aq[it];
            uint2 pk;
            pk.x = (unsigned)f2bf(q.x) | ((unsigned)f2bf(q.y) << 16);
            pk.y = (unsigned)f2bf(q.z) | ((unsigned)f2bf(q.w) << 16);
            *(uint2*)&sa[R * SA_S + (R & 31) + rq] = pk;   // (R&31)+rq ≡ 0 mod 4
        }
    }
    #pragma unroll
    for (int it = 0; it < 3; ++it) {
        int lin = tid + it * 256;
        if (lin < TILE * 5) {
            int R = lin / 5, e = lin - R * 5;
            int r0 = (4 - (R & 3)) & 3;
            int r = (e < r0) ? e : 60 + e;
            sa[R * SA_S + (R & 31) + r] = f2bf(ae[it]);
        }
    }

    __syncthreads();

    // ---- MFMA: wave w -> rows [t0+32w, +32), two 32-col blocks of f ----
    const int lane = tid & 63;
    const int wv   = tid >> 6;
    const int n    = lane & 31;
    const int hi   = lane >> 5;
    const int Rw   = 32 * wv + n;

    f32x16 acc0 = {};
    f32x16 acc1 = {};

    #pragma unroll
    for (int kb = 0; kb < 6; ++kb) {
        const int cp = kb * 16 + hi * 8;      // k within tile-local axis
        const int c  = 32 * wv + cp;          // block-level v column
        bf16x8 af = *(const bf16x8*)&sa[Rw * SA_S + cp];
        bf16x8 b0 = *(const bf16x8*)&sv[n * SV_S + c];
        bf16x8 b1 = *(const bf16x8*)&sv[(n + 32) * SV_S + c];
        acc0 = __builtin_amdgcn_mfma_f32_32x32x16_bf16(af, b0, acc0, 0, 0, 0);
        acc1 = __builtin_amdgcn_mfma_f32_32x32x16_bf16(af, b1, acc1, 0, 0, 0);
    }

    // C/D: col = lane&31, row = (reg&3) + 8*(reg>>2) + 4*(lane>>5)  [m74/m101]
    float* op = out + ((size_t)bh * TT + t0 + 32 * wv) * FF;
    #pragma unroll
    for (int reg = 0; reg < 16; ++reg) {
        int row = (reg & 3) + 8 * (reg >> 2) + 4 * hi;
        op[row * FF + n]      = acc0[reg];
        op[row * FF + 32 + n] = acc1[reg];
    }
}

extern "C" void kernel_launch(void* const* d_in, const int* in_sizes, int n_in,
                              void* d_out, int out_size, void* d_ws, size_t ws_size,
                              hipStream_t stream) {
    const float* a = (const float*)d_in[0];
    const float* v = (const float*)d_in[1];
    float* out = (float*)d_out;

    const int BH = in_sizes[1] / (TT * FF);      // 128
    const int grid = BH * (TT / TILE);           // 4096 blocks

    unfold_mfma<<<grid, 256, 0, stream>>>(a, v, out);
}

// Round 4
// 93.137 us; speedup vs baseline: 4.7530x; 1.1332x over previous
//
#include <hip/hip_runtime.h>

// out[b,h,t,f] = sum_{r=0..64} a[b,h,t,r] * v[b,h, t+r-32, f]  (zero-padded in t)
// B=8 H=16 T=4096 F=64 R=65, fp32 in/out. Threshold 1.0 -> bf16 MFMA safe (r3: absmax 0.25).
//
// Banded matmul on matrix cores. Round 4: TILE 128->64 so LDS = 30.2 KB ->
// 5 blocks/CU (20 waves) instead of 3 (12 waves); round-3 counters showed
// latency-bound (VALU 15%, HBM 26%, occ 31%), not BW-bound.
// Per block: 4 waves, wave (wr,wc) computes rows [t0+32wr,+32) x cols [32wc,+32)
//   OUT(32x64) = Ablk(32x96) x Vslice(96x64),
//   Ablk[i][k] = (0 <= k-i <= 64) ? a[t0+32wr+i][k-i] : 0   (band densified)

#define TT 4096
#define RRR 65
#define FF 64
#define TILE 64
#define SA_S 104     // bf16 row stride: 208B rows -> 4-way on af b128 (benign)
#define SV_S 132     // bf16 row stride: 264B rows -> 2-way (free) on b b128

typedef short bf16x8 __attribute__((ext_vector_type(8)));
typedef float f32x16 __attribute__((ext_vector_type(16)));

__device__ __forceinline__ unsigned short f2bf(float x) {
    unsigned int u = __float_as_uint(x);
    u += 0x7fff + ((u >> 16) & 1);            // RNE
    return (unsigned short)(u >> 16);
}

__global__ __launch_bounds__(256, 5)
void unfold_mfma(const float* __restrict__ a, const float* __restrict__ v,
                 float* __restrict__ out) {
    __shared__ __align__(16) unsigned short sa[TILE * SA_S];  // 13312 B
    __shared__ __align__(16) unsigned short sv[FF * SV_S];    // 16896 B

    const int tid  = threadIdx.x;
    const int bh   = blockIdx.x >> 6;       // 64 tiles per (b,h)
    const int tile = blockIdx.x & 63;
    const int t0   = tile << 6;

    const float* arow = a + ((size_t)bh * TT + t0) * RRR;   // 16B-aligned (t0*65%4==0)
    const float* vsl  = v + (size_t)bh * TT * FF;

    // ---- zero-prefill sa (band complement must be 0): 832 uint4 ----
    {
        uint4 z = make_uint4(0, 0, 0, 0);
        uint4* sp = (uint4*)sa;
        #pragma unroll
        for (int it = 0; it < 4; ++it) {
            int lin = tid + it * 256;
            if (lin < (TILE * SA_S) / 8) sp[lin] = z;
        }
    }

    // ---- preload a (consumed after barrier) ----
    // per row R: aligned quads at r = r0+4j, j<15  ((R*65+r0)%4==0), + 5 edge elems
    float4 aq[4];
    #pragma unroll
    for (int it = 0; it < 4; ++it) {
        int lin = tid + it * 256;
        if (lin < TILE * 15) {
            int R = lin / 15, j = lin - R * 15;
            int r0 = (4 - (R & 3)) & 3;
            aq[it] = *(const float4*)(arow + (size_t)R * RRR + r0 + 4 * j);
        }
    }
    float ae[2];
    #pragma unroll
    for (int it = 0; it < 2; ++it) {
        int lin = tid + it * 256;
        if (lin < TILE * 5) {
            int R = lin / 5, e = lin - R * 5;
            int r0 = (4 - (R & 3)) & 3;
            int r = (e < r0) ? e : 60 + e;    // head [0,r0) + tail [r0+60,64]
            ae[it] = arow[(size_t)R * RRR + r];
        }
    }

    // ---- stage v transposed: sv[f][c] = bf16(v[t0-32+c][f]), c in [0,128) ----
    {
        const int f  = tid & 63;
        const int wv = tid >> 6;
        #pragma unroll
        for (int it = 0; it < 8; ++it) {
            int cb = 32 * wv + 4 * it;
            int g  = t0 - 32 + cb;
            float x0 = (g + 0 >= 0 && g + 0 < TT) ? vsl[(size_t)(g + 0) * FF + f] : 0.f;
            float x1 = (g + 1 >= 0 && g + 1 < TT) ? vsl[(size_t)(g + 1) * FF + f] : 0.f;
            float x2 = (g + 2 >= 0 && g + 2 < TT) ? vsl[(size_t)(g + 2) * FF + f] : 0.f;
            float x3 = (g + 3 >= 0 && g + 3 < TT) ? vsl[(size_t)(g + 3) * FF + f] : 0.f;
            uint2 pk;
            pk.x = (unsigned)f2bf(x0) | ((unsigned)f2bf(x1) << 16);
            pk.y = (unsigned)f2bf(x2) | ((unsigned)f2bf(x3) << 16);
            *(uint2*)&sv[f * SV_S + cb] = pk;
        }
    }

    __syncthreads();   // prefill visible before band scatter

    // ---- scatter a band: sa[R][(R&31) + r] = bf16(a[t0+R][r]) ----
    #pragma unroll
    for (int it = 0; it < 4; ++it) {
        int lin = tid + it * 256;
        if (lin < TILE * 15) {
            int R = lin / 15, j = lin - R * 15;
            int r0 = (4 - (R & 3)) & 3;
            int rq = r0 + 4 * j;
            float4 q = aq[it];
            uint2 pk;
            pk.x = (unsigned)f2bf(q.x) | ((unsigned)f2bf(q.y) << 16);
            pk.y = (unsigned)f2bf(q.z) | ((unsigned)f2bf(q.w) << 16);
            *(uint2*)&sa[R * SA_S + (R & 31) + rq] = pk;   // (R&31)+rq ≡ 0 mod 4
        }
    }
    #pragma unroll
    for (int it = 0; it < 2; ++it) {
        int lin = tid + it * 256;
        if (lin < TILE * 5) {
            int R = lin / 5, e = lin - R * 5;
            int r0 = (4 - (R & 3)) & 3;
            int r = (e < r0) ? e : 60 + e;
            sa[R * SA_S + (R & 31) + r] = f2bf(ae[it]);
        }
    }

    __syncthreads();

    // ---- MFMA: wave (wr,wc) -> rows [t0+32wr,+32), cols [32wc,+32) ----
    const int lane = tid & 63;
    const int wv   = tid >> 6;
    const int wr   = wv >> 1;
    const int wc   = wv & 1;
    const int n    = lane & 31;
    const int hi   = lane >> 5;
    const int Rw   = 32 * wr + n;

    f32x16 acc = {};
    #pragma unroll
    for (int kb = 0; kb < 6; ++kb) {
        const int cp = kb * 16 + hi * 8;        // k within the row-tile's 96-band
        bf16x8 af = *(const bf16x8*)&sa[Rw * SA_S + cp];
        bf16x8 bf = *(const bf16x8*)&sv[(32 * wc + n) * SV_S + (32 * wr + cp)];
        acc = __builtin_amdgcn_mfma_f32_32x32x16_bf16(af, bf, acc, 0, 0, 0);
    }

    // C/D: col = lane&31, row = (reg&3) + 8*(reg>>2) + 4*(lane>>5)  [m74/m101]
    float* op = out + ((size_t)bh * TT + t0 + 32 * wr) * FF + 32 * wc;
    #pragma unroll
    for (int reg = 0; reg < 16; ++reg) {
        int row = (reg & 3) + 8 * (reg >> 2) + 4 * hi;
        op[row * FF + n] = acc[reg];
    }
}

extern "C" void kernel_launch(void* const* d_in, const int* in_sizes, int n_in,
                              void* d_out, int out_size, void* d_ws, size_t ws_size,
                              hipStream_t stream) {
    const float* a = (const float*)d_in[0];
    const float* v = (const float*)d_in[1];
    float* out = (float*)d_out;

    const int BH = in_sizes[1] / (TT * FF);      // 128
    const int grid = BH * (TT / TILE);           // 8192 blocks

    unfold_mfma<<<grid, 256, 0, stream>>>(a, v, out);
}

// Round 6
// 75.461 us; speedup vs baseline: 5.8663x; 1.2342x over previous
//
#include <hip/hip_runtime.h>

// out[b,h,t,f] = sum_{r=0..64} a[b,h,t,r] * v[b,h, t+r-32, f]  (zero-padded in t)
// B=8 H=16 T=4096 F=64 R=65, fp32 in/out. bf16 MFMA (r3/r4: absmax 0.25 vs thr 1.0).
//
// Round 6 = round 5 with the compile fix (__floats2bfloat162_rn doesn't exist in
// ROCm 7.2 -> use the proven RNE bit-twiddle from rounds 3/4).
// Persistent blocks + cross-tile software pipeline: each block runs 8 tiles of one
// (b,h): SCATTER(i); bar; ISSUE(i+1); COMPUTE+STORE(i); bar -- tile i+1's global
// loads (in registers) overlap tile i's compute, removing VMEM latency from the
// critical path. sa zero-prefill hoisted (band pattern identical every tile).

#define TT 4096
#define RRR 65
#define FF 64
#define TILE 64
#define SA_S 100     // bf16 row stride: 200B rows -> 2-way (free) on A b128 reads
#define SV_S 132     // bf16 row stride: 264B rows -> 2-way (free) on B b128 reads
#define NTPB 8       // tiles per block (8 | 64 -> bh constant per block)

typedef short bf16x8 __attribute__((ext_vector_type(8)));
typedef float f32x16 __attribute__((ext_vector_type(16)));

__device__ __forceinline__ unsigned short f2bf(float x) {
    unsigned int u = __float_as_uint(x);
    u += 0x7fff + ((u >> 16) & 1);            // RNE
    return (unsigned short)(u >> 16);
}
__device__ __forceinline__ unsigned pk2(float lo, float hi) {
    return (unsigned)f2bf(lo) | ((unsigned)f2bf(hi) << 16);
}

__global__ __launch_bounds__(256, 4)
void unfold_mfma(const float* __restrict__ a, const float* __restrict__ v,
                 float* __restrict__ out) {
    __shared__ __align__(16) unsigned short sa[TILE * SA_S];  // 12800 B
    __shared__ __align__(16) unsigned short sv[FF * SV_S];    // 16896 B

    const int tid = threadIdx.x;
    const int f   = tid & 63;
    const int wv  = tid >> 6;

    const int bh = blockIdx.x >> 3;                 // 8 blocks per (b,h)
    const float* vsl = v + (size_t)bh * TT * FF;
    const size_t obase = (size_t)bh * TT * FF;

    // ---- one-time zero-prefill of sa (band complement stays 0 across tiles) ----
    {
        uint4 z = make_uint4(0, 0, 0, 0);
        uint4* sp = (uint4*)sa;
        #pragma unroll
        for (int it = 0; it < 4; ++it) {
            int lin = tid + it * 256;
            if (lin < (TILE * SA_S) / 8) sp[lin] = z;
        }
    }

    float4 aq[4];
    float  ae[2];
    float  vv[8][4];

    int t0 = ((blockIdx.x & 7) * NTPB) << 6;
    const float* arow = a + ((size_t)bh * TT + t0) * RRR;

    // ---- load issue: a quads (aligned), a edges, v slab (interior fast path) ----
#define ISSUE_LOADS() do {                                                     \
    _Pragma("unroll")                                                          \
    for (int it = 0; it < 4; ++it) {                                           \
        int lin = tid + it * 256;                                              \
        if (lin < TILE * 15) {                                                 \
            int R = lin / 15, j = lin - R * 15;                                \
            int r0 = (4 - (R & 3)) & 3;                                        \
            aq[it] = *(const float4*)(arow + (size_t)R * RRR + r0 + 4 * j);    \
        }                                                                      \
    }                                                                          \
    _Pragma("unroll")                                                          \
    for (int it = 0; it < 2; ++it) {                                           \
        int lin = tid + it * 256;                                              \
        if (lin < TILE * 5) {                                                  \
            int R = lin / 5, e = lin - R * 5;                                  \
            int r0 = (4 - (R & 3)) & 3;                                        \
            int r = (e < r0) ? e : 60 + e;                                     \
            ae[it] = arow[(size_t)R * RRR + r];                                \
        }                                                                      \
    }                                                                          \
    {                                                                          \
        const int gb = t0 - 32 + 32 * wv;                                      \
        if (t0 >= 32 && t0 + 96 <= TT) {                                       \
            _Pragma("unroll")                                                  \
            for (int it = 0; it < 8; ++it)                                     \
                _Pragma("unroll")                                              \
                for (int j = 0; j < 4; ++j)                                    \
                    vv[it][j] = vsl[(size_t)(gb + 4 * it + j) * FF + f];       \
        } else {                                                               \
            _Pragma("unroll")                                                  \
            for (int it = 0; it < 8; ++it)                                     \
                _Pragma("unroll")                                              \
                for (int j = 0; j < 4; ++j) {                                  \
                    int g = gb + 4 * it + j;                                   \
                    vv[it][j] = (g >= 0 && g < TT)                             \
                                ? vsl[(size_t)g * FF + f] : 0.f;               \
                }                                                              \
        }                                                                      \
    }                                                                          \
} while (0)

    // ---- convert + LDS scatter of the staged registers ----
#define SCATTER() do {                                                         \
    _Pragma("unroll")                                                          \
    for (int it = 0; it < 4; ++it) {                                           \
        int lin = tid + it * 256;                                              \
        if (lin < TILE * 15) {                                                 \
            int R = lin / 15, j = lin - R * 15;                                \
            int r0 = (4 - (R & 3)) & 3;                                        \
            int rq = r0 + 4 * j;                                               \
            float4 q = aq[it];                                                 \
            uint2 pw; pw.x = pk2(q.x, q.y); pw.y = pk2(q.z, q.w);              \
            *(uint2*)&sa[R * SA_S + (R & 31) + rq] = pw;                       \
        }                                                                      \
    }                                                                          \
    _Pragma("unroll")                                                          \
    for (int it = 0; it < 2; ++it) {                                           \
        int lin = tid + it * 256;                                              \
        if (lin < TILE * 5) {                                                  \
            int R = lin / 5, e = lin - R * 5;                                  \
            int r0 = (4 - (R & 3)) & 3;                                        \
            int r = (e < r0) ? e : 60 + e;                                     \
            sa[R * SA_S + (R & 31) + r] = f2bf(ae[it]);                        \
        }                                                                      \
    }                                                                          \
    _Pragma("unroll")                                                          \
    for (int it = 0; it < 8; ++it) {                                           \
        uint2 pw; pw.x = pk2(vv[it][0], vv[it][1]);                            \
        pw.y = pk2(vv[it][2], vv[it][3]);                                      \
        *(uint2*)&sv[f * SV_S + 32 * wv + 4 * it] = pw;                        \
    }                                                                          \
} while (0)

    ISSUE_LOADS();
    __syncthreads();   // prefill visible before first band scatter

    const int n  = f & 31;
    const int hi = f >> 5;
    const int wr = wv >> 1;
    const int wc = wv & 1;
    const int Rw = 32 * wr + n;

    #pragma unroll 1
    for (int i = 0; i < NTPB; ++i) {
        SCATTER();
        const int cur_t0 = t0;
        __syncthreads();

        if (i + 1 < NTPB) {
            t0 += TILE;
            arow = a + ((size_t)bh * TT + t0) * RRR;
            ISSUE_LOADS();           // overlaps compute+stores below
        }

        // ---- MFMA: wave (wr,wc) -> rows [cur_t0+32wr,+32), cols [32wc,+32) ----
        f32x16 acc = {};
        #pragma unroll
        for (int kb = 0; kb < 6; ++kb) {
            const int cp = kb * 16 + hi * 8;
            bf16x8 af = *(const bf16x8*)&sa[Rw * SA_S + cp];
            bf16x8 bv = *(const bf16x8*)&sv[(32 * wc + n) * SV_S + (32 * wr + cp)];
            acc = __builtin_amdgcn_mfma_f32_32x32x16_bf16(af, bv, acc, 0, 0, 0);
        }

        // C/D: col = lane&31, row = (reg&3) + 8*(reg>>2) + 4*(lane>>5)
        float* op = out + obase + (size_t)(cur_t0 + 32 * wr) * FF + 32 * wc;
        #pragma unroll
        for (int reg = 0; reg < 16; ++reg) {
            int row = (reg & 3) + 8 * (reg >> 2) + 4 * hi;
            __builtin_nontemporal_store(acc[reg], &op[row * FF + n]);
        }
        __syncthreads();             // LDS free for next scatter
    }
}

extern "C" void kernel_launch(void* const* d_in, const int* in_sizes, int n_in,
                              void* d_out, int out_size, void* d_ws, size_t ws_size,
                              hipStream_t stream) {
    const float* a = (const float*)d_in[0];
    const float* v = (const float*)d_in[1];
    float* out = (float*)d_out;

    const int BH = in_sizes[1] / (TT * FF);          // 128
    const int grid = BH * (TT / TILE) / NTPB;        // 1024 blocks

    unfold_mfma<<<grid, 256, 0, stream>>>(a, v, out);
}